// Round 1
// baseline (372.066 us; speedup 1.0000x reference)
//
#include <hip/hip_runtime.h>

// Problem constants
#define SEQ   2048
#define BATCH 16
#define CINCH 512
#define HDIM  512
#define NDIM  1536            // 3*H
#define TBM   (SEQ*BATCH)     // 32768 = GEMM M
#define KRED  1024            // Cin*K = GEMM K

typedef unsigned short ushort_t;
typedef __bf16 bf16x8 __attribute__((ext_vector_type(8)));
typedef unsigned short u16x8 __attribute__((ext_vector_type(8)));
typedef float f32x4 __attribute__((ext_vector_type(4)));

__device__ __forceinline__ float bf2f(ushort_t u) {
    return __uint_as_float(((unsigned int)u) << 16);
}
__device__ __forceinline__ ushort_t f2bf(float x) {
    unsigned int u = __float_as_uint(x);
    unsigned int r = u + 0x7fffu + ((u >> 16) & 1u);   // round-to-nearest-even
    return (ushort_t)(r >> 16);
}

// ---------------------------------------------------------------------------
// Kernel 1: cast x (fp32, T*B*Cin) -> bf16 with a BATCH*CINCH zero prefix so
// row m of the "concat" A-matrix is [xbpad row m (t-1 tap), xbpad row m+B (t tap)]
// ---------------------------------------------------------------------------
__global__ void cast_x_kernel(const float* __restrict__ x, ushort_t* __restrict__ xb) {
    int i = blockIdx.x * 256 + threadIdx.x;   // one group of 4 elements
    int e = i * 4;
    ushort4 r;
    if (e < BATCH * CINCH) {
        r.x = 0; r.y = 0; r.z = 0; r.w = 0;
    } else {
        float4 v = *(const float4*)(x + (e - BATCH * CINCH));
        r.x = f2bf(v.x); r.y = f2bf(v.y); r.z = f2bf(v.z); r.w = f2bf(v.w);
    }
    *(ushort4*)(xb + e) = r;
}

// ---------------------------------------------------------------------------
// Kernel 2: repack W (3H, Cin, K=2) fp32 -> Wb (3H, 1024) bf16 where
// Wb[o][k*512+ci] = W[o][ci][k]  (pairs with xcat column order)
// ---------------------------------------------------------------------------
__global__ void repack_w_kernel(const float* __restrict__ W, ushort_t* __restrict__ wb) {
    int i = blockIdx.x * 256 + threadIdx.x;   // 0 .. 1536*1024
    int o  = i >> 10;
    int r  = i & 1023;
    int k  = r >> 9;
    int ci = r & 511;
    wb[i] = f2bf(W[o * 1024 + ci * 2 + k]);
}

// ---------------------------------------------------------------------------
// Kernel 3: GEMM g[m,n] = sum_j xcat[m,j]*Wb[n,j] + bias[n]; fused activation;
// write bf16 gate arrays z/f/o each laid out [T*B][H].
// 128x128 tile, BK=64, 4 waves (2x2), 16x16x32 bf16 MFMA, XOR-swizzled LDS,
// global_load_lds width=16 staging.
// ---------------------------------------------------------------------------
__device__ __forceinline__ void load_lds_16B(const ushort_t* g, ushort_t* l) {
    auto* gp = reinterpret_cast<const __attribute__((address_space(1))) unsigned int*>(
        reinterpret_cast<uintptr_t>(g));
    auto* lp = reinterpret_cast<__attribute__((address_space(3))) unsigned int*>(
        reinterpret_cast<uintptr_t>(l));
    __builtin_amdgcn_global_load_lds(gp, lp, 16, 0, 0);
}

__global__ __launch_bounds__(256) void gemm_gates_kernel(
    const ushort_t* __restrict__ xb, const ushort_t* __restrict__ wb,
    const float* __restrict__ bias,
    ushort_t* __restrict__ zb, ushort_t* __restrict__ fb, ushort_t* __restrict__ ob) {

    __shared__ ushort_t As[128 * 64];
    __shared__ ushort_t Bs[128 * 64];

    const int tid  = threadIdx.x;
    const int w    = tid >> 6;
    const int lane = tid & 63;
    const int quad = lane >> 4;
    const int l15  = lane & 15;
    const int wm   = w & 1;
    const int wn   = w >> 1;
    const int mBase = blockIdx.x * 128;
    const int nBase = blockIdx.y * 128;

    const int srow = lane >> 3;   // 0..7 row within 8-row staging group
    const int scb  = lane & 7;    // physical colblock this lane fills

    f32x4 acc[4][4];
#pragma unroll
    for (int i = 0; i < 4; ++i)
#pragma unroll
        for (int j = 0; j < 4; ++j)
            acc[i][j] = (f32x4){0.f, 0.f, 0.f, 0.f};

    for (int kt = 0; kt < 16; ++kt) {
        __syncthreads();   // previous iter's ds_reads done before overwrite
        // element offset into xbpad for this K-tile: tap0 (j<512) reads row m,
        // tap1 (j>=512) reads row m+BATCH (= +16*512 elements)
        const long aOff = (kt < 8) ? (long)kt * 64 : (long)16 * 512 + (long)(kt - 8) * 64;
#pragma unroll
        for (int i = 0; i < 4; ++i) {
            const int row = w * 32 + i * 8 + srow;           // tile-local row
            const int cbd = scb ^ (row & 7);                  // swizzled data colblock
            const ushort_t* ga = xb + (long)(mBase + row) * 512 + aOff + cbd * 8;
            load_lds_16B(ga, &As[(w * 32 + i * 8) * 64]);
            const ushort_t* gb = wb + (long)(nBase + row) * 1024 + kt * 64 + cbd * 8;
            load_lds_16B(gb, &Bs[(w * 32 + i * 8) * 64]);
        }
        __syncthreads();   // drains vmcnt(0): staging complete

#pragma unroll
        for (int ks = 0; ks < 2; ++ks) {
            bf16x8 af[4], bfr[4];
            const int cbd = ks * 4 + quad;
#pragma unroll
            for (int mt = 0; mt < 4; ++mt) {
                int ml  = wm * 64 + mt * 16 + l15;
                int off = ml * 64 + ((cbd ^ (ml & 7)) * 8);
                af[mt] = __builtin_bit_cast(bf16x8, *(const u16x8*)(&As[off]));
            }
#pragma unroll
            for (int nt = 0; nt < 4; ++nt) {
                int nl  = wn * 64 + nt * 16 + l15;
                int off = nl * 64 + ((cbd ^ (nl & 7)) * 8);
                bfr[nt] = __builtin_bit_cast(bf16x8, *(const u16x8*)(&Bs[off]));
            }
#pragma unroll
            for (int mt = 0; mt < 4; ++mt)
#pragma unroll
                for (int nt = 0; nt < 4; ++nt)
                    acc[mt][nt] = __builtin_amdgcn_mfma_f32_16x16x32_bf16(
                        af[mt], bfr[nt], acc[mt][nt], 0, 0, 0);
        }
    }

    // Epilogue: bias + activation, scatter to gate arrays (bf16)
#pragma unroll
    for (int nt = 0; nt < 4; ++nt) {
        const int n    = nBase + wn * 64 + nt * 16 + l15;
        const int gate = n >> 9;
        const int h    = n & 511;
        const float bv = bias[n];
        ushort_t* outp = (gate == 0) ? zb : (gate == 1) ? fb : ob;
#pragma unroll
        for (int mt = 0; mt < 4; ++mt) {
#pragma unroll
            for (int r = 0; r < 4; ++r) {
                int m   = mBase + wm * 64 + mt * 16 + quad * 4 + r;
                float g = acc[mt][nt][r] + bv;
                float a;
                if (gate == 0) {
                    // tanh via exp of negative arg (no overflow)
                    float e = __expf(-2.f * fabsf(g));
                    float t = (1.f - e) / (1.f + e);
                    a = copysignf(t, g);
                } else {
                    a = 1.f / (1.f + __expf(-g));
                }
                outp[(long)m * 512 + h] = f2bf(a);
            }
        }
    }
}

// ---------------------------------------------------------------------------
// Kernel 4: sequential fo-pool scan over T. 8192 independent chains (B*H).
// c = f*c + (1-f)*z ; h = c*o. Software-pipelined with U=16 prefetch window.
// out = [hs (T*B*H)] [h_last (B*H)] [c_last (B*H)]
// ---------------------------------------------------------------------------
__global__ void scan_kernel(const ushort_t* __restrict__ zb,
                            const ushort_t* __restrict__ fb,
                            const ushort_t* __restrict__ ob,
                            float* __restrict__ out) {
    const int col = blockIdx.x * 64 + threadIdx.x;   // 0..8191
    const int U = 16;
    float zc[U], fc[U], oc[U];
    float c = 0.f, h = 0.f;

#pragma unroll
    for (int u = 0; u < U; ++u) {
        int idx = u * 8192 + col;
        zc[u] = bf2f(zb[idx]); fc[u] = bf2f(fb[idx]); oc[u] = bf2f(ob[idx]);
    }
    for (int t0 = 0; t0 < SEQ; t0 += U) {
        float zn[U], fn[U], on[U];
        if (t0 + U < SEQ) {
#pragma unroll
            for (int u = 0; u < U; ++u) {
                int idx = (t0 + U + u) * 8192 + col;
                zn[u] = bf2f(zb[idx]); fn[u] = bf2f(fb[idx]); on[u] = bf2f(ob[idx]);
            }
        } else {
#pragma unroll
            for (int u = 0; u < U; ++u) { zn[u] = 0.f; fn[u] = 0.f; on[u] = 0.f; }
        }
#pragma unroll
        for (int u = 0; u < U; ++u) {
            c = fc[u] * c + (1.f - fc[u]) * zc[u];
            h = c * oc[u];
            out[(t0 + u) * 8192 + col] = h;
        }
#pragma unroll
        for (int u = 0; u < U; ++u) { zc[u] = zn[u]; fc[u] = fn[u]; oc[u] = on[u]; }
    }
    out[(long)SEQ * 8192 + col] = h;          // h_last
    out[(long)SEQ * 8192 + 8192 + col] = c;   // c_last
}

// ---------------------------------------------------------------------------
extern "C" void kernel_launch(void* const* d_in, const int* in_sizes, int n_in,
                              void* d_out, int out_size, void* d_ws, size_t ws_size,
                              hipStream_t stream) {
    const float* x  = (const float*)d_in[0];   // (T, B, Cin)
    const float* W  = (const float*)d_in[1];   // (3H, Cin, 2)
    const float* bi = (const float*)d_in[2];   // (3H,)
    float* out = (float*)d_out;

    char* ws = (char*)d_ws;
    const size_t xbN = (size_t)(TBM + BATCH) * CINCH;   // padded bf16 x
    const size_t wbN = (size_t)NDIM * KRED;
    const size_t gN  = (size_t)TBM * HDIM;
    ushort_t* xb = (ushort_t*)ws;
    ushort_t* wb = (ushort_t*)(ws + xbN * 2);
    ushort_t* zb = (ushort_t*)(ws + xbN * 2 + wbN * 2);
    ushort_t* fb = zb + gN;
    ushort_t* ob = fb + gN;

    // 1) cast + zero-pad x:  (TBM+BATCH)*CINCH/4 groups = 4,196,352 -> 16392 blocks
    cast_x_kernel<<<16392, 256, 0, stream>>>(x, xb);
    // 2) repack W: 1536*1024/256 = 6144 blocks
    repack_w_kernel<<<6144, 256, 0, stream>>>(W, wb);
    // 3) GEMM + gates: grid (M/128, N/128) = (256, 12)
    dim3 ggrid(TBM / 128, NDIM / 128);
    gemm_gates_kernel<<<ggrid, 256, 0, stream>>>(xb, wb, bi, zb, fb, ob);
    // 4) scan: 8192 chains, 64 threads/block over 128 blocks (spread across CUs)
    scan_kernel<<<128, 64, 0, stream>>>(zb, fb, ob, out);
}

// Round 2
// 292.613 us; speedup vs baseline: 1.2715x; 1.2715x over previous
//
#include <hip/hip_runtime.h>

// Problem constants
#define SEQ   2048
#define BATCH 16
#define CINCH 512
#define HDIM  512
#define NDIM  1536            // 3*H
#define TBM   (SEQ*BATCH)     // 32768 = GEMM M
#define KRED  1024            // Cin*K = GEMM K
#define NCH   32              // scan chunks
#define CHL   64              // chunk length (NCH*CHL == SEQ)
#define NCOL  8192            // B*H chains

typedef unsigned short ushort_t;
typedef __bf16 bf16x8 __attribute__((ext_vector_type(8)));
typedef unsigned short u16x8 __attribute__((ext_vector_type(8)));
typedef float f32x4 __attribute__((ext_vector_type(4)));

__device__ __forceinline__ float bf2f(ushort_t u) {
    return __uint_as_float(((unsigned int)u) << 16);
}
__device__ __forceinline__ ushort_t f2bf(float x) {
    unsigned int u = __float_as_uint(x);
    unsigned int r = u + 0x7fffu + ((u >> 16) & 1u);   // round-to-nearest-even
    return (ushort_t)(r >> 16);
}

// ---------------------------------------------------------------------------
// Kernel 1: cast x (fp32, T*B*Cin) -> bf16 with a BATCH*CINCH zero prefix so
// row m of the "concat" A-matrix is [xbpad row m (t-1 tap), xbpad row m+B (t tap)]
// ---------------------------------------------------------------------------
__global__ void cast_x_kernel(const float* __restrict__ x, ushort_t* __restrict__ xb) {
    int i = blockIdx.x * 256 + threadIdx.x;
    int e = i * 4;
    ushort4 r;
    if (e < BATCH * CINCH) {
        r.x = 0; r.y = 0; r.z = 0; r.w = 0;
    } else {
        float4 v = *(const float4*)(x + (e - BATCH * CINCH));
        r.x = f2bf(v.x); r.y = f2bf(v.y); r.z = f2bf(v.z); r.w = f2bf(v.w);
    }
    *(ushort4*)(xb + e) = r;
}

// ---------------------------------------------------------------------------
// Kernel 2: repack W (3H, Cin, K=2) fp32 -> Wb (3H, 1024) bf16 where
// Wb[o][k*512+ci] = W[o][ci][k]
// ---------------------------------------------------------------------------
__global__ void repack_w_kernel(const float* __restrict__ W, ushort_t* __restrict__ wb) {
    int i = blockIdx.x * 256 + threadIdx.x;
    int o  = i >> 10;
    int r  = i & 1023;
    int k  = r >> 9;
    int ci = r & 511;
    wb[i] = f2bf(W[o * 1024 + ci * 2 + k]);
}

// ---------------------------------------------------------------------------
// Kernel 3: GEMM + bias + activation -> bf16 gates z/f/o, each [T*B][H].
// 128x128 tile, BK=64, 4 waves, 16x16x32 bf16 MFMA, XOR-swizzled LDS,
// global_load_lds width=16 staging. Epilogue: LDS transpose so global
// stores are 256B-contiguous row segments (kills write amplification).
// ---------------------------------------------------------------------------
__device__ __forceinline__ void load_lds_16B(const ushort_t* g, ushort_t* l) {
    auto* gp = reinterpret_cast<const __attribute__((address_space(1))) unsigned int*>(
        reinterpret_cast<uintptr_t>(g));
    auto* lp = reinterpret_cast<__attribute__((address_space(3))) unsigned int*>(
        reinterpret_cast<uintptr_t>(l));
    __builtin_amdgcn_global_load_lds(gp, lp, 16, 0, 0);
}

__global__ __launch_bounds__(256) void gemm_gates_kernel(
    const ushort_t* __restrict__ xb, const ushort_t* __restrict__ wb,
    const float* __restrict__ bias,
    ushort_t* __restrict__ zb, ushort_t* __restrict__ fb, ushort_t* __restrict__ ob) {

    __shared__ ushort_t smem[2 * 128 * 64];   // As/Bs during K-loop; 128x128 out-tile in epilogue
    ushort_t* As = smem;
    ushort_t* Bs = smem + 128 * 64;

    const int tid  = threadIdx.x;
    const int w    = tid >> 6;
    const int lane = tid & 63;
    const int quad = lane >> 4;
    const int l15  = lane & 15;
    const int wm   = w & 1;
    const int wn   = w >> 1;
    const int mBase = blockIdx.x * 128;
    const int nBase = blockIdx.y * 128;

    const int srow = lane >> 3;
    const int scb  = lane & 7;

    f32x4 acc[4][4];
#pragma unroll
    for (int i = 0; i < 4; ++i)
#pragma unroll
        for (int j = 0; j < 4; ++j)
            acc[i][j] = (f32x4){0.f, 0.f, 0.f, 0.f};

    for (int kt = 0; kt < 16; ++kt) {
        __syncthreads();
        const long aOff = (kt < 8) ? (long)kt * 64 : (long)16 * 512 + (long)(kt - 8) * 64;
#pragma unroll
        for (int i = 0; i < 4; ++i) {
            const int row = w * 32 + i * 8 + srow;
            const int cbd = scb ^ (row & 7);
            const ushort_t* ga = xb + (long)(mBase + row) * 512 + aOff + cbd * 8;
            load_lds_16B(ga, &As[(w * 32 + i * 8) * 64]);
            const ushort_t* gb = wb + (long)(nBase + row) * 1024 + kt * 64 + cbd * 8;
            load_lds_16B(gb, &Bs[(w * 32 + i * 8) * 64]);
        }
        __syncthreads();

#pragma unroll
        for (int ks = 0; ks < 2; ++ks) {
            bf16x8 af[4], bfr[4];
            const int cbd = ks * 4 + quad;
#pragma unroll
            for (int mt = 0; mt < 4; ++mt) {
                int ml  = wm * 64 + mt * 16 + l15;
                int off = ml * 64 + ((cbd ^ (ml & 7)) * 8);
                af[mt] = __builtin_bit_cast(bf16x8, *(const u16x8*)(&As[off]));
            }
#pragma unroll
            for (int nt = 0; nt < 4; ++nt) {
                int nl  = wn * 64 + nt * 16 + l15;
                int off = nl * 64 + ((cbd ^ (nl & 7)) * 8);
                bfr[nt] = __builtin_bit_cast(bf16x8, *(const u16x8*)(&Bs[off]));
            }
#pragma unroll
            for (int mt = 0; mt < 4; ++mt)
#pragma unroll
                for (int nt = 0; nt < 4; ++nt)
                    acc[mt][nt] = __builtin_amdgcn_mfma_f32_16x16x32_bf16(
                        af[mt], bfr[nt], acc[mt][nt], 0, 0, 0);
        }
    }

    // ---- Epilogue: bias + activation into LDS (swizzled), then coalesced stores
    const int gate = nBase >> 9;            // block-uniform: 4 N-tiles per gate
    const int hb   = nBase & 511;

    __syncthreads();   // everyone done reading As/Bs
#pragma unroll
    for (int nt = 0; nt < 4; ++nt) {
        const int n_local = wn * 64 + nt * 16 + l15;
        const float bv = bias[nBase + n_local];
#pragma unroll
        for (int mt = 0; mt < 4; ++mt) {
#pragma unroll
            for (int r = 0; r < 4; ++r) {
                const int m_local = wm * 64 + mt * 16 + quad * 4 + r;
                float g = acc[mt][nt][r] + bv;
                float a;
                if (gate == 0) {
                    float e = __expf(-2.f * fabsf(g));
                    float t = (1.f - e) / (1.f + e);
                    a = copysignf(t, g);
                } else {
                    a = 1.f / (1.f + __expf(-g));
                }
                const int phys = ((n_local >> 3) ^ (m_local & 7)) * 8 + (n_local & 7);
                smem[m_local * 128 + phys] = f2bf(a);
            }
        }
    }
    __syncthreads();

    ushort_t* outp = (gate == 0) ? zb : (gate == 1) ? fb : ob;
#pragma unroll
    for (int s = 0; s < 8; ++s) {
        const int m_local = w * 32 + s * 4 + quad;
        const int blk = l15 ^ (m_local & 7);   // phys block holding logical block l15
        u16x8 v = *(const u16x8*)(&smem[m_local * 128 + blk * 8]);
        *(u16x8*)(outp + (long)(mBase + m_local) * 512 + hb + l15 * 8) = v;
    }
}

// ---------------------------------------------------------------------------
// Scan, chunked-parallel (3 passes). c = f*c + (1-f)*z ; h = c*o.
// ---------------------------------------------------------------------------
__global__ __launch_bounds__(256) void scan_compose(
    const ushort_t* __restrict__ zb, const ushort_t* __restrict__ fb,
    float* __restrict__ Acomp, float* __restrict__ Bcomp) {
    const int col = (blockIdx.x & 31) * 256 + threadIdx.x;
    const int ch  = blockIdx.x >> 5;
    const long base = (long)ch * CHL * NCOL + col;
    float A = 1.f, Bv = 0.f;
    const int U = 16;
    for (int w0 = 0; w0 < CHL; w0 += U) {
        float zc[U], fc[U];
#pragma unroll
        for (int u = 0; u < U; ++u) {
            long idx = base + (long)(w0 + u) * NCOL;
            zc[u] = bf2f(zb[idx]); fc[u] = bf2f(fb[idx]);
        }
#pragma unroll
        for (int u = 0; u < U; ++u) {
            Bv = fc[u] * Bv + (1.f - fc[u]) * zc[u];
            A *= fc[u];
        }
    }
    Acomp[ch * NCOL + col] = A;
    Bcomp[ch * NCOL + col] = Bv;
}

__global__ void scan_prefix(const float* __restrict__ Acomp,
                            const float* __restrict__ Bcomp,
                            float* __restrict__ Cin) {
    const int col = blockIdx.x * 256 + threadIdx.x;
    float c = 0.f;
#pragma unroll 4
    for (int ch = 0; ch < NCH; ++ch) {
        Cin[ch * NCOL + col] = c;
        c = Acomp[ch * NCOL + col] * c + Bcomp[ch * NCOL + col];
    }
}

__global__ __launch_bounds__(256) void scan_apply(
    const ushort_t* __restrict__ zb, const ushort_t* __restrict__ fb,
    const ushort_t* __restrict__ ob, const float* __restrict__ Cin,
    float* __restrict__ out) {
    const int col = (blockIdx.x & 31) * 256 + threadIdx.x;
    const int ch  = blockIdx.x >> 5;
    const long base = (long)ch * CHL * NCOL + col;
    float c = Cin[ch * NCOL + col];
    float h = 0.f;
    const int U = 16;
    for (int w0 = 0; w0 < CHL; w0 += U) {
        float zc[U], fc[U], oc[U];
#pragma unroll
        for (int u = 0; u < U; ++u) {
            long idx = base + (long)(w0 + u) * NCOL;
            zc[u] = bf2f(zb[idx]); fc[u] = bf2f(fb[idx]); oc[u] = bf2f(ob[idx]);
        }
#pragma unroll
        for (int u = 0; u < U; ++u) {
            c = fc[u] * c + (1.f - fc[u]) * zc[u];
            h = c * oc[u];
            out[base + (long)(w0 + u) * NCOL] = h;
        }
    }
    if (ch == NCH - 1) {
        out[(long)SEQ * NCOL + col] = h;           // h_last
        out[(long)SEQ * NCOL + NCOL + col] = c;    // c_last
    }
}

// ---------------------------------------------------------------------------
extern "C" void kernel_launch(void* const* d_in, const int* in_sizes, int n_in,
                              void* d_out, int out_size, void* d_ws, size_t ws_size,
                              hipStream_t stream) {
    const float* x  = (const float*)d_in[0];   // (T, B, Cin)
    const float* W  = (const float*)d_in[1];   // (3H, Cin, 2)
    const float* bi = (const float*)d_in[2];   // (3H,)
    float* out = (float*)d_out;

    char* ws = (char*)d_ws;
    const size_t xbN = (size_t)(TBM + BATCH) * CINCH;   // padded bf16 x
    const size_t wbN = (size_t)NDIM * KRED;
    const size_t gN  = (size_t)TBM * HDIM;
    ushort_t* xb = (ushort_t*)ws;
    ushort_t* wb = (ushort_t*)(ws + xbN * 2);
    ushort_t* zb = (ushort_t*)(ws + xbN * 2 + wbN * 2);
    ushort_t* fb = zb + gN;
    ushort_t* ob = fb + gN;
    // scan scratch reuses the xb region (dead after the GEMM): 3 MB << 33.5 MB
    float* Acomp = (float*)ws;
    float* Bcomp = Acomp + NCH * NCOL;
    float* Cin   = Bcomp + NCH * NCOL;

    cast_x_kernel<<<16392, 256, 0, stream>>>(x, xb);
    repack_w_kernel<<<6144, 256, 0, stream>>>(W, wb);
    dim3 ggrid(TBM / 128, NDIM / 128);
    gemm_gates_kernel<<<ggrid, 256, 0, stream>>>(xb, wb, bi, zb, fb, ob);
    scan_compose<<<NCH * 32, 256, 0, stream>>>(zb, fb, Acomp, Bcomp);
    scan_prefix<<<NCOL / 256, 256, 0, stream>>>(Acomp, Bcomp, Cin);
    scan_apply<<<NCH * 32, 256, 0, stream>>>(zb, fb, ob, Cin, out);
}